// Round 1
// 156.997 us; speedup vs baseline: 1.0714x; 1.0714x over previous
//
#include <hip/hip_runtime.h>
#include <stdint.h>

#define IN_DIM 4096
#define H_DIM  2048
#define NPTS   2097152

typedef short  bf16x8  __attribute__((ext_vector_type(8)));
typedef float  floatx4 __attribute__((ext_vector_type(4)));

#define AS1 __attribute__((address_space(1)))
#define AS3 __attribute__((address_space(3)))

__device__ __forceinline__ unsigned short f2bf(float f) {
    unsigned u = __float_as_uint(f);
    unsigned r = (u + 0x7FFFu + ((u >> 16) & 1u)) >> 16;   // RNE
    return (unsigned short)r;
}

// ---------------- Kernel 1: prep_h + prep_w2t merged; also zeros rowsum ----------------
__global__ void prep_all(const float* __restrict__ W1, const float* __restrict__ b1,
                         const float* __restrict__ W2,
                         unsigned short* __restrict__ hbf, unsigned short* __restrict__ W2T,
                         float* __restrict__ rowsum) {
    __shared__ unsigned short tile[64][66];
    int b = blockIdx.x;
    if (b < 8192) {
        if (b < 16) rowsum[b * 256 + threadIdx.x] = 0.0f;   // 16*256 = 4096
        int idx = (b * 256 + threadIdx.x) * 4;              // covers 8388608
        float4 w = *(const float4*)(W1 + idx);
        float4 bb = *(const float4*)(b1 + (idx & (H_DIM - 1)));
        ushort4 o;
        o.x = f2bf(tanhf(w.x + bb.x));
        o.y = f2bf(tanhf(w.y + bb.y));
        o.z = f2bf(tanhf(w.z + bb.z));
        o.w = f2bf(tanhf(w.w + bb.w));
        *(ushort4*)(hbf + idx) = o;
    } else {
        int bb = b - 8192;
        int k0 = (bb >> 5) * 64, n0 = (bb & 31) * 64;
        for (int idx = threadIdx.x; idx < 64 * 64; idx += 256) {
            int r = idx >> 6, c = idx & 63;             // c fast -> coalesced read of W2 row
            tile[c][r] = f2bf(W2[(size_t)(k0 + r) * H_DIM + n0 + c]);
        }
        __syncthreads();
        for (int idx = threadIdx.x; idx < 64 * 64; idx += 256) {
            int r = idx >> 6, c = idx & 63;             // c fast -> coalesced write of W2T row
            W2T[(size_t)(n0 + r) * H_DIM + k0 + c] = tile[r][c];
        }
    }
}

// ---------------- Kernel 2: fused GEMM + tanh + @W3 row-reduce ----------------
// 128x128 tile (m97-proven shape: 912 TF at 4096^3), 512 blocks (2/CU).
// Two-barrier single-buffer K-loop (proven control flow). BK=64; 32 KB LDS.
// Compute/staging = 64 FLOP/B (was 42.7 at 128x64); MFMA:ds_read = 2.0 (was 1.33).
// Staging: each global_load_lds covers 8 rows x 128 B. Lane l -> row (l>>3),
// DATA chunk (l&7)^(l>>3) (XOR swizzle in what is fetched, landing at slot l*16B).
//   -> global: 8-lane groups each cover one contiguous 128 B segment (coalesced)
//   -> LDS layout: elem(r,k) @ r*64 + ((k>>3)^(r&7))*8 + (k&7)
//   -> fragment ds_read_b128: slot cs=(s*4+quad)^(lane16&7); cs%8 distinct within
//      every 8-lane phase group -> 0 bank conflicts AND coalesced staging.
// __launch_bounds__(256,2): grid only allows 2 blocks/CU; don't cap VGPR at 128
// (acc[4][4]=64 + frags 32 + addressing ~= 110-125 regs).
#define BK 64
__global__ __launch_bounds__(256, 2) void gemm_fused(
    const unsigned short* __restrict__ A,    // 4096 x 2048 bf16 (h)
    const unsigned short* __restrict__ BT,   // 2048 x 2048 bf16 (W2^T, N x K)
    const float* __restrict__ b2, const float* __restrict__ W3,
    float* __restrict__ rowsum) {
    __shared__ __align__(16) unsigned short As[128 * BK];   // 16 KB
    __shared__ __align__(16) unsigned short Bs[128 * BK];   // 16 KB
    const int K = H_DIM;
    const int t = threadIdx.x;
    const int w = t >> 6, l = t & 63;
    const int lane16 = l & 15, quad = l >> 4;
    const int wr = w >> 1, wc = w & 1;                      // 2x2 waves over 128x128
    const int rowBase = blockIdx.y * 128;
    const int colBase = blockIdx.x * 128;

    // per-lane staging offset within an 8-row group (elements)
    const int sRow = l >> 3;                   // 0..7
    const int sChunk = (l & 7) ^ sRow;         // swizzled data chunk
    const size_t laneOff = (size_t)sRow * K + sChunk * 8;

    // wave w stages A rows [w*32, w*32+32) in 4 instrs, B rows [w*32, w*32+32) in 4
    const unsigned short* aBase = A  + (size_t)(rowBase + w * 32) * K + laneOff;
    const unsigned short* bBase = BT + (size_t)(colBase + w * 32) * K + laneOff;

    floatx4 acc[4][4];
    floatx4 zero = {0.f, 0.f, 0.f, 0.f};
#pragma unroll
    for (int i = 0; i < 4; ++i)
#pragma unroll
        for (int j = 0; j < 4; ++j) acc[i][j] = zero;

    for (int k0 = 0; k0 < K; k0 += BK) {
        __syncthreads();          // prior iteration's ds_reads done; LDS reusable
#pragma unroll
        for (int i = 0; i < 4; ++i)
            __builtin_amdgcn_global_load_lds(
                (const AS1 void*)(aBase + (size_t)i * 8 * K + k0),
                (AS3 void*)(As + (w * 32 + i * 8) * 64), 16, 0, 0);
#pragma unroll
        for (int i = 0; i < 4; ++i)
            __builtin_amdgcn_global_load_lds(
                (const AS1 void*)(bBase + (size_t)i * 8 * K + k0),
                (AS3 void*)(Bs + (w * 32 + i * 8) * 64), 16, 0, 0);
        __syncthreads();          // vmcnt(0) drain: tile ready

#pragma unroll
        for (int s = 0; s < 2; ++s) {   // two 16x16x32 k-steps within BK=64
            const int cs = (s * 4 + quad) ^ (lane16 & 7);
            bf16x8 af[4], bfr[4];
#pragma unroll
            for (int mi = 0; mi < 4; ++mi)
                af[mi] = *(const bf16x8*)(As + (wr * 64 + mi * 16 + lane16) * 64 + cs * 8);
#pragma unroll
            for (int ni = 0; ni < 4; ++ni)
                bfr[ni] = *(const bf16x8*)(Bs + (wc * 64 + ni * 16 + lane16) * 64 + cs * 8);
#pragma unroll
            for (int mi = 0; mi < 4; ++mi)
#pragma unroll
                for (int ni = 0; ni < 4; ++ni)
                    acc[mi][ni] = __builtin_amdgcn_mfma_f32_16x16x32_bf16(
                        af[mi], bfr[ni], acc[mi][ni], 0, 0, 0);
        }
    }

    // Epilogue: C/D layout col=lane&15, row=quad*4+reg
    const int rowG = rowBase + wr * 64;
#pragma unroll
    for (int mi = 0; mi < 4; ++mi) {
#pragma unroll
        for (int r = 0; r < 4; ++r) {
            float s = 0.f;
#pragma unroll
            for (int ni = 0; ni < 4; ++ni) {
                int col = colBase + wc * 64 + ni * 16 + lane16;
                float v = acc[mi][ni][r] + b2[col];
                s += tanhf(v) * W3[col];
            }
#pragma unroll
            for (int off = 1; off < 16; off <<= 1) s += __shfl_xor(s, off, 64);
            if (lane16 == 0)
                atomicAdd(&rowsum[rowG + mi * 16 + quad * 4 + r], s);
        }
    }
}

// ---------------- Kernel 3: spline gather, 2 points/thread, fused u=3*tanh(rowsum+b3) ----------------
__device__ __forceinline__ float spline_eval(const float* us, float ptx, float pty) {
    float x = (ptx + 1.0f) * 0.5f;
    float px = x * 62.0f, py = pty * 62.0f;
    float fx = floorf(px), fy = floorf(py);
    int posx = min((int)fx + 1, 62);
    int posy = min((int)fy + 1, 62);
    float tx = px - fx, ty = py - fy;
    float bx0 = 0.5f * (1.f - tx) * (1.f - tx);
    float bx1 = -tx * tx + tx + 0.5f;
    float bx2 = 0.5f * tx * tx;
    float by0 = 0.5f * (1.f - ty) * (1.f - ty);
    float by1 = -ty * ty + ty + 0.5f;
    float by2 = 0.5f * ty * ty;
    const float* r0 = &us[(posx - 1) * 64 + (posy - 1)];
    const float* r1 = r0 + 64;
    const float* r2 = r1 + 64;
    float s0 = r0[0] * by0 + r0[1] * by1 + r0[2] * by2;
    float s1 = r1[0] * by0 + r1[1] * by1 + r1[2] * by2;
    float s2 = r2[0] * by0 + r2[1] * by1 + r2[2] * by2;
    return bx0 * s0 + bx1 * s1 + bx2 * s2;
}

__global__ void spline_kernel(const float4* __restrict__ pts,
                              const float* __restrict__ rowsum,
                              const float* __restrict__ b3,
                              float2* __restrict__ out, int npairs) {
    __shared__ float us[4096];
    float bias = b3[0];
    for (int i = threadIdx.x; i < 4096; i += blockDim.x)
        us[i] = 3.0f * tanhf(rowsum[i] + bias);
    __syncthreads();
    int stride = gridDim.x * blockDim.x;
    for (int idx = blockIdx.x * blockDim.x + threadIdx.x; idx < npairs; idx += stride) {
        float4 p2 = pts[idx];     // two points
        float2 o;
        o.x = spline_eval(us, p2.x, p2.y);
        o.y = spline_eval(us, p2.z, p2.w);
        out[idx] = o;
    }
}

extern "C" void kernel_launch(void* const* d_in, const int* in_sizes, int n_in,
                              void* d_out, int out_size, void* d_ws, size_t ws_size,
                              hipStream_t stream) {
    const float* points = (const float*)d_in[0];
    const float* W1 = (const float*)d_in[1];
    const float* b1 = (const float*)d_in[2];
    const float* W2 = (const float*)d_in[3];
    const float* b2 = (const float*)d_in[4];
    const float* W3 = (const float*)d_in[5];
    const float* b3 = (const float*)d_in[6];
    float* out = (float*)d_out;

    char* ws = (char*)d_ws;
    unsigned short* hbf = (unsigned short*)ws;                        // 16777216 B
    unsigned short* w2t = (unsigned short*)(ws + 16777216);           //  8388608 B
    float* rowsum = (float*)(ws + 25165824);                          //    16384 B

    prep_all<<<8192 + 1024, 256, 0, stream>>>(W1, b1, W2, hbf, w2t, rowsum);
    gemm_fused<<<dim3(H_DIM / 128, IN_DIM / 128), 256, 0, stream>>>(hbf, w2t, b2, W3, rowsum);
    spline_kernel<<<1024, 256, 0, stream>>>((const float4*)points, rowsum, b3,
                                            (float2*)out, NPTS / 2);
}